// Round 5
// baseline (199.071 us; speedup 1.0000x reference)
//
#include <hip/hip_runtime.h>
#include <limits.h>

#define BATCH 50
#define MAX_ATOMS 21000
#define DIM 128
#define ROW4 (DIM / 4)                      // 32 float4 per feature row
#define TOTAL4 (BATCH * MAX_ATOMS * ROW4)   // 33,600,000 float4 outputs
#define BLOCK 256
#define F4_PER_THREAD 4
#define F4_PER_BLOCK (BLOCK * F4_PER_THREAD)  // 1024 f4 = 32 output rows

typedef float f4 __attribute__((ext_vector_type(4)));

// Fused kernel: each block covers 32 output rows spanning partitions
// {b0, b0+1} (b0 static from blockIdx). Waves 0..2 compute the 3 needed
// lower_bounds (starts[b0], starts[b0+1], starts[b0+2]) via 64-ary wave
// search over the sorted index array (L2/L3-resident, ~5 dependent probe
// rounds), then all threads stream the gather with NT load/store pairs.
// Handles int32 or int64 index storage (int64 little-endian small values
// viewed as int32 -> descending adjacent pair near the middle).
__global__ __launch_bounds__(BLOCK) void fused_gather_pad_kernel(
        const f4* __restrict__ feat,
        const int* __restrict__ idx32, int N,
        f4* __restrict__ out) {
    __shared__ int s_st[3];

    const unsigned int row0 = (blockIdx.x * (unsigned)F4_PER_BLOCK) >> 5;
    const unsigned int b0   = row0 / MAX_ATOMS;     // first partition touched

    const int wave = threadIdx.x >> 6;
    const int lane = threadIdx.x & 63;

    if (wave < 3) {
        // per-wave int64 storage detection (ballot over adjacent pairs)
        int mid = N / 2;
        int a0 = idx32[mid + lane];
        int a1 = idx32[mid + lane + 1];
        const int stride = (__ballot(a0 > a1) != 0ull) ? 2 : 1;

        int t = (int)b0 + wave;                     // search target
        if (t > BATCH) t = BATCH;                   // lower_bound(BATCH) == N

        long L = 0, H = N;                          // answer in [L, H]
        while (H - L > 64) {
            long len  = H - L;
            long step = (len + 63) >> 6;            // ceil(len/64)
            long p = L + (long)lane * step;
            int  v = (p < H) ? idx32[p * stride] : INT_MAX;
            int  c = __popcll(__ballot(v < t));
            long oldL = L;
            if (c == 0) { H = L; break; }
            L = oldL + (long)(c - 1) * step + 1;
            long nh = oldL + (long)c * step;
            if (nh < H) H = nh;
        }
        long p = L + lane;
        int  v = (p < H) ? idx32[p * stride] : INT_MAX;
        int  c = __popcll(__ballot(v < t));
        if (lane == 0) s_st[wave] = (int)(L + c);
    }
    __syncthreads();

    const int s0 = s_st[0], s1 = s_st[1], s2 = s_st[2];

    unsigned int base = blockIdx.x * (unsigned)F4_PER_BLOCK + threadIdx.x;
#pragma unroll
    for (int k = 0; k < F4_PER_THREAD; ++k) {
        unsigned int gid = base + (unsigned)k * BLOCK;
        if (gid < (unsigned)TOTAL4) {
            unsigned int q   = gid & (ROW4 - 1);
            unsigned int row = gid >> 5;            // b * MAX_ATOMS + p
            unsigned int b   = row / MAX_ATOMS;     // magic-mul
            unsigned int p   = row - b * MAX_ATOMS;
            int lb = (int)(b - b0);                 // 0 or 1 within this block
            int s  = lb ? s1 : s0;
            int e  = lb ? s2 : s1;
            f4 v = (f4)(0.0f);
            if ((int)p < e - s)
                v = __builtin_nontemporal_load(feat + (long)(s + (int)p) * ROW4 + q);
            __builtin_nontemporal_store(v, out + gid);
        }
    }
}

extern "C" void kernel_launch(void* const* d_in, const int* in_sizes, int n_in,
                              void* d_out, int out_size, void* d_ws, size_t ws_size,
                              hipStream_t stream) {
    const float* feat = (const float*)d_in[0];
    const int*   idx  = (const int*)d_in[1];
    int N = in_sizes[1];                    // 1,000,000 atoms

    const int grid = (TOTAL4 + F4_PER_BLOCK - 1) / F4_PER_BLOCK;
    fused_gather_pad_kernel<<<grid, BLOCK, 0, stream>>>(
        (const f4*)feat, idx, N, (f4*)d_out);
}

// Round 6
// 182.403 us; speedup vs baseline: 1.0914x; 1.0914x over previous
//
#include <hip/hip_runtime.h>
#include <limits.h>

#define BATCH 50
#define MAX_ATOMS 21000
#define DIM 128
#define ROW4 (DIM / 4)                      // 32 float4 per feature row
#define TOTAL4 (BATCH * MAX_ATOMS * ROW4)   // 33,600,000 float4 outputs
#define BLOCK 256
#define F4_PER_THREAD 4
#define F4_PER_BLOCK (BLOCK * F4_PER_THREAD)  // 1024

typedef float f4 __attribute__((ext_vector_type(4)));

// Kernel 1: starts[b] = lower_bound(idx, b), one wave per b, 64-ary search.
// Each probe round narrows the bracket by 64x -> 4 dependent HBM round trips
// (1M -> 15625 -> 245 -> 4 -> done). Handles int32 or int64 index storage
// (int64 little-endian small values viewed as int32 -> descending adjacent
// pair near the middle).
__global__ __launch_bounds__(1024) void compute_starts_kernel(
        const int* __restrict__ idx32, int N, int* __restrict__ starts) {
    const int lane = threadIdx.x & 63;
    const int b = (int)(blockIdx.x * 16u + (threadIdx.x >> 6));  // wave id
    if (b > BATCH) return;

    // int64 storage detection (uniform result per wave via ballot)
    int base = N / 2;
    int a0 = idx32[base + lane];
    int a1 = idx32[base + lane + 1];
    const int stride = (__ballot(a0 > a1) != 0ull) ? 2 : 1;

    long L = 0, H = N;   // lower_bound(idx, b) is in [L, H]
    while (H - L > 64) {
        long len = H - L;
        long step = (len + 63) >> 6;          // ceil(len/64)
        long p = L + (long)lane * step;
        int v = (p < H) ? idx32[p * stride] : INT_MAX;
        int c = __popcll(__ballot(v < b));
        long oldL = L;
        if (c == 0) { H = L; break; }         // answer == L
        L = oldL + (long)(c - 1) * step + 1;
        long nh = oldL + (long)c * step;
        if (nh < H) H = nh;
    }
    // final round: bracket width <= 64
    long p = L + lane;
    int v = (p < H) ? idx32[p * stride] : INT_MAX;
    int c = __popcll(__ballot(v < b));
    if (lane == 0) starts[b] = (int)(L + c);
}

// Kernel 2: gather-style padded write, 4 float4 per thread, NT streams,
// load+store paired per iteration (proven fastest shape, R2/R4).
// out[b][p][q] = (p < count[b]) ? feat[(starts[b]+p)*ROW4 + q] : 0
__global__ __launch_bounds__(BLOCK) void gather_pad_kernel(
        const f4* __restrict__ feat,
        const int* __restrict__ starts,
        f4* __restrict__ out) {
    __shared__ int s_starts[BATCH + 1];
    if (threadIdx.x <= BATCH) s_starts[threadIdx.x] = starts[threadIdx.x];
    __syncthreads();

    unsigned int base = blockIdx.x * (unsigned)F4_PER_BLOCK + threadIdx.x;
#pragma unroll
    for (int k = 0; k < F4_PER_THREAD; ++k) {
        unsigned int gid = base + (unsigned)k * BLOCK;
        if (gid < (unsigned)TOTAL4) {
            unsigned int q   = gid & (ROW4 - 1);
            unsigned int row = gid >> 5;              // b * MAX_ATOMS + p
            unsigned int b   = row / MAX_ATOMS;       // magic-mul
            unsigned int p   = row - b * MAX_ATOMS;
            int s = s_starts[b];
            int e = s_starts[b + 1];
            f4 v = (f4)(0.0f);
            if ((int)p < e - s)
                v = __builtin_nontemporal_load(feat + (long)(s + (int)p) * ROW4 + q);
            __builtin_nontemporal_store(v, out + gid);
        }
    }
}

extern "C" void kernel_launch(void* const* d_in, const int* in_sizes, int n_in,
                              void* d_out, int out_size, void* d_ws, size_t ws_size,
                              hipStream_t stream) {
    const float* feat = (const float*)d_in[0];
    const int*   idx  = (const int*)d_in[1];
    int N = in_sizes[1];                    // 1,000,000 atoms

    int* starts = (int*)d_ws;               // BATCH+1 ints of scratch

    // 4 blocks x 16 waves = 64 waves >= 51 searches
    compute_starts_kernel<<<4, 1024, 0, stream>>>(idx, N, starts);

    const int grid = (TOTAL4 + F4_PER_BLOCK - 1) / F4_PER_BLOCK;
    gather_pad_kernel<<<grid, BLOCK, 0, stream>>>(
        (const f4*)feat, starts, (f4*)d_out);
}